// Round 20
// baseline (97.192 us; speedup 1.0000x reference)
//
#include <hip/hip_runtime.h>
#include <hip/hip_bf16.h>

typedef unsigned short u16;
typedef __bf16 bf16x8 __attribute__((ext_vector_type(8)));
typedef float f32x4 __attribute__((ext_vector_type(4)));
typedef float f32x16 __attribute__((ext_vector_type(16)));
typedef unsigned short ushort8 __attribute__((ext_vector_type(8)));

#define C_IN   128
#define C_OUT  256
#define BATCH  16
#define LEN    4096
#define KS     9
#define PAD    4
#define KTOT   (C_IN * KS)        // 1152
#define NSTEP  72                 // K = 1152 / 16

#define W5_BLKS    1152           // 294912 / 256
#define EB_BLKS    256

__device__ inline u16 f2bf(float f) {
    __hip_bfloat16 h = __float2bfloat16(f);
    return __builtin_bit_cast(u16, h);
}

// ---------------------------------------------------------------------------
// Prep (unchanged): w5 repack + ebias + phys.
// ---------------------------------------------------------------------------
__global__ void prep_all(const float* __restrict__ w,
                         const float* __restrict__ bias, const float* __restrict__ vel,
                         const float* __restrict__ acc_in,
                         u16* __restrict__ w5,
                         float* __restrict__ ebias, float* __restrict__ phys_out) {
    int bid = blockIdx.x;
    int t = threadIdx.x;
    if (bid < W5_BLKS) {
        int i = bid * 256 + t;               // 294912 total
        int e    = i & 7;
        int lane = (i >> 3) & 63;
        int g    = (i >> 9) & 7;
        int s    = i >> 12;                  // 0..71
        int o    = g * 32 + (lane & 31);
        int hi   = lane >> 5;
        int c    = (s & 7) * 16 + hi * 8 + e;
        int k    = s >> 3;
        w5[i] = f2bf(w[((size_t)o * C_IN + c) * KS + k]);
        return;
    }
    __shared__ float red[256];
    int o = bid - W5_BLKS;
    float sum = 0.f;
    for (int i = t; i < KTOT; i += 256) {
        int k = i % KS;                    // offset layout [c][k]
        float tk = k * 0.01f;              // DT
        float off = vel[i] * tk + 0.5f * acc_in[i] * tk * tk;
        sum += off * w[(size_t)o * KTOT + i];
    }
    red[t] = sum;
    __syncthreads();
    for (int h = 128; h > 0; h >>= 1) {
        if (t < h) red[t] += red[t + h];
        __syncthreads();
    }
    if (t == 0) ebias[o] = bias[o] + red[0];

    if (o == 0) {                          // phys
        __syncthreads();
        float pv = 0.f;
        for (int i = t; i < KTOT; i += 256) {
            float v = vel[i], a = acc_in[i];
            pv += v * v + a * a;
        }
        red[t] = pv;
        __syncthreads();
        for (int h = 128; h > 0; h >>= 1) {
            if (t < h) red[t] += red[t + h];
            __syncthreads();
        }
        if (t == 0) *phys_out = 0.01f * (red[0] / (float)KTOT);
    }
}

// ---------------------------------------------------------------------------
// Main: R15 base (fused transpose, swizzled B-LDS, w5 lane-order A, 32x32
// MFMA, barrier-free loop) restructured as TWO SEQUENTIAL HALF-PASSES per
// wave (64o x 128l each, acc[2][4]=128 regs REUSED between passes — unlike
// R18 there is never a second live accumulator set, so no spill pressure).
// Purpose: pass 0's 32.8MB of output stores are issued BEFORE pass 1's
// ~19us K-loop, so their HBM drain overlaps compute. Tests the terminal-
// write-burst theory (the last standing explanation of the 41.5us wall:
// all blocks finish K in lockstep and drain 65.5MB with nothing overlapping
// it; reproduces 16.2us MFMA + burst = 41.5us, and explains why no load-
// side schedule ever moved the needle).
// K-loop: triple-buffered registers, prefetch distance 2 (R12's proven
// rotation; 8-MFMA clusters = 258cyc need >1-step cover for ~200-250cyc L2).
// ---------------------------------------------------------------------------
__global__ __launch_bounds__(128, 1) void conv_main(const float* __restrict__ x,
                                                    const u16* __restrict__ w5,
                                                    const float* __restrict__ ebias,
                                                    float* __restrict__ out) {
    __shared__ u16 ldsx[17408];            // B tile: 136 rows x 256B = 34816 B

    int b     = blockIdx.y;
    int lbase = blockIdx.x * 128;
    int t     = threadIdx.x;               // 0..127
    int lane  = t & 63;
    int wm    = t >> 6;                    // wave = o-half (128 o each)
    int l31   = lane & 31;
    int hi    = lane >> 5;

    // ---- fused B-tile transpose+cast+swizzle (unchanged from R15) ----
    const float* xb = x + (size_t)b * C_IN * LEN;
    {
        // phase 1: rows 0..127, one row per thread; lanes = consecutive l
        int r = t;
        int l = lbase + r - PAD;
        l = l < 0 ? 0 : (l > LEN - 1 ? LEN - 1 : l);
        int key = r & 15;
        float v[16][8];
        #pragma unroll
        for (int cb = 0; cb < 16; ++cb)
            #pragma unroll
            for (int e = 0; e < 8; ++e)
                v[cb][e] = xb[(size_t)(cb * 8 + e) * LEN + l];   // coalesced
        #pragma unroll
        for (int cb = 0; cb < 16; ++cb) {
            ushort8 u;
            #pragma unroll
            for (int e = 0; e < 8; ++e) u[e] = f2bf(v[cb][e]);
            *reinterpret_cast<ushort8*>(ldsx + r * 128 + ((cb ^ key) * 8)) = u;
        }
    }
    {
        // phase 2: halo rows 128..135, (row, cblk) unit per thread
        int r  = 128 + (t & 7);
        int cb = t >> 3;                   // 0..15
        int l = lbase + r - PAD;
        l = l < 0 ? 0 : (l > LEN - 1 ? LEN - 1 : l);
        ushort8 u;
        #pragma unroll
        for (int e = 0; e < 8; ++e)
            u[e] = f2bf(xb[(size_t)(cb * 8 + e) * LEN + l]);
        *reinterpret_cast<ushort8*>(ldsx + r * 128 + ((cb ^ (r & 15)) * 8)) = u;
    }
    __syncthreads();                       // B-tile ready; the only barrier

    const char* ldsbase = reinterpret_cast<const char*>(ldsx);

    #define LOAD_A2(AP, S, AF)                                                   \
        {                                                                        \
            const u16* p_ = (AP) + (size_t)(S) * 4096;                           \
            AF[0] = *reinterpret_cast<const bf16x8*>(p_);                        \
            AF[1] = *reinterpret_cast<const bf16x8*>(p_ + 512);                  \
        }
    #define LOAD_B(S, BF)                                                        \
        {                                                                        \
            int k_ = (S) >> 3;                                                   \
            int sl_ = ((S) & 7) * 2 + hi;                                        \
            _Pragma("unroll")                                                    \
            for (int nj = 0; nj < 4; ++nj) {                                     \
                int row_  = nj * 32 + l31 + k_;                                  \
                int addr_ = row_ * 256 + ((sl_ ^ (row_ & 15)) << 4);             \
                BF[nj] = *reinterpret_cast<const bf16x8*>(ldsbase + addr_);      \
            }                                                                    \
        }
    #define MFMA8(AF, BF)                                                        \
        {                                                                        \
            _Pragma("unroll")                                                    \
            for (int mi = 0; mi < 2; ++mi)                                       \
                _Pragma("unroll")                                                \
                for (int nj = 0; nj < 4; ++nj)                                   \
                    acc[mi][nj] = __builtin_amdgcn_mfma_f32_32x32x16_bf16(       \
                        AF[mi], BF[nj], acc[mi][nj], 0, 0, 0);                   \
        }
    // One half-pass: K=1152 over mi-pair {P*2, P*2+1}, then store its 64x128
    // quarter. Pass 0's stores precede pass 1's K-loop -> overlapped drain.
    #define RUN_PASS(P)                                                          \
        {                                                                        \
            const u16* ap_ = w5 + ((size_t)(wm * 4 + (P) * 2) * 64 + lane) * 8;  \
            f32x16 acc[2][4] = {};                                               \
            bf16x8 aA[2], aB[2], aC[2], bA[4], bB[4], bC[4];                     \
            LOAD_A2(ap_, 0, aA); LOAD_B(0, bA);                                  \
            LOAD_A2(ap_, 1, aB); LOAD_B(1, bB);                                  \
            _Pragma("unroll")                                                    \
            for (int s = 0; s < NSTEP; s += 3) {   /* 72 = 3*24 exact */         \
                if (s + 2 < NSTEP) { LOAD_A2(ap_, s + 2, aC); LOAD_B(s + 2, bC); } \
                MFMA8(aA, bA);                                                   \
                if (s + 3 < NSTEP) { LOAD_A2(ap_, s + 3, aA); LOAD_B(s + 3, bA); } \
                MFMA8(aB, bB);                                                   \
                if (s + 4 < NSTEP) { LOAD_A2(ap_, s + 4, aB); LOAD_B(s + 4, bB); } \
                if (s + 2 < NSTEP) MFMA8(aC, bC);                                \
            }                                                                    \
            _Pragma("unroll")                                                    \
            for (int mi = 0; mi < 2; ++mi) {                                     \
                int o0 = wm * 128 + ((P) * 2 + mi) * 32 + hi * 4;                \
                _Pragma("unroll")                                                \
                for (int nj = 0; nj < 4; ++nj) {                                 \
                    int l = lbase + nj * 32 + l31;                               \
                    _Pragma("unroll")                                            \
                    for (int q = 0; q < 4; ++q) {                                \
                        f32x4 eb = *reinterpret_cast<const f32x4*>(ebias + o0 + q * 8); \
                        float* op = out + (size_t)(b * C_OUT + o0 + q * 8) * LEN + l;   \
                        _Pragma("unroll")                                        \
                        for (int p2 = 0; p2 < 4; ++p2)                           \
                            op[(size_t)p2 * LEN] = acc[mi][nj][q * 4 + p2] + eb[p2];    \
                    }                                                            \
                }                                                                \
            }                                                                    \
        }

    RUN_PASS(0);                           // stores issued here drain under...
    RUN_PASS(1);                           // ...this pass's ~19us K-loop

    #undef LOAD_A2
    #undef LOAD_B
    #undef MFMA8
    #undef RUN_PASS
}

extern "C" void kernel_launch(void* const* d_in, const int* in_sizes, int n_in,
                              void* d_out, int out_size, void* d_ws, size_t ws_size,
                              hipStream_t stream) {
    const float* x      = (const float*)d_in[0];
    const float* weight = (const float*)d_in[1];
    const float* bias   = (const float*)d_in[2];
    const float* vel    = (const float*)d_in[3];
    const float* acc    = (const float*)d_in[4];
    float* out = (float*)d_out;

    char* ws = (char*)d_ws;
    u16*  w5    = (u16*)ws;                                   // 589,824 B
    float* ebias = (float*)(ws + (size_t)C_OUT * KTOT * 2);

    hipLaunchKernelGGL(prep_all, dim3(W5_BLKS + EB_BLKS), dim3(256), 0, stream,
                       weight, bias, vel, acc, w5, ebias,
                       out + (size_t)BATCH * C_OUT * LEN);
    hipLaunchKernelGGL(conv_main, dim3(LEN / 128, BATCH), dim3(128), 0, stream,
                       x, w5, ebias, out);
}

// Round 21
// 52.068 us; speedup vs baseline: 1.8666x; 1.8666x over previous
//
#include <hip/hip_runtime.h>
#include <hip/hip_bf16.h>

typedef unsigned short u16;
typedef __bf16 bf16x8 __attribute__((ext_vector_type(8)));
typedef float f32x4 __attribute__((ext_vector_type(4)));
typedef float f32x16 __attribute__((ext_vector_type(16)));
typedef unsigned short ushort8 __attribute__((ext_vector_type(8)));

#define C_IN   128
#define C_OUT  256
#define BATCH  16
#define LEN    4096
#define KS     9
#define PAD    4
#define KTOT   (C_IN * KS)        // 1152
#define NSTEP  72                 // K = 1152 / 16

#define W5_BLKS    1152           // 294912 / 256
#define EB_BLKS    256

__device__ inline u16 f2bf(float f) {
    __hip_bfloat16 h = __float2bfloat16(f);
    return __builtin_bit_cast(u16, h);
}

// ---------------------------------------------------------------------------
// Prep (small, one launch):
//  blocks [0,1152): weight -> w5 in 32-lane fragment order for
//    mfma_f32_32x32x16_bf16:  i = ((s*8 + g)*64 + lane)*8 + e  where
//    o = g*32 + (lane&31), hi = lane>>5, c = (s&7)*16 + hi*8 + e, k = s>>3.
//  blocks [1152,1408): ebias[o] = bias[o] + sum offset*W; block 1152: phys.
// The offset term (vel*t + 0.5*acc*t^2) is (b,l)-independent, so by
// linearity it folds into a per-channel effective bias — the whole
// "Galilean" modification costs 256 dot products, not a 4D unfold.
// ---------------------------------------------------------------------------
__global__ void prep_all(const float* __restrict__ w,
                         const float* __restrict__ bias, const float* __restrict__ vel,
                         const float* __restrict__ acc_in,
                         u16* __restrict__ w5,
                         float* __restrict__ ebias, float* __restrict__ phys_out) {
    int bid = blockIdx.x;
    int t = threadIdx.x;
    if (bid < W5_BLKS) {
        int i = bid * 256 + t;               // 294912 total
        int e    = i & 7;
        int lane = (i >> 3) & 63;
        int g    = (i >> 9) & 7;
        int s    = i >> 12;                  // 0..71
        int o    = g * 32 + (lane & 31);
        int hi   = lane >> 5;
        int c    = (s & 7) * 16 + hi * 8 + e;
        int k    = s >> 3;
        w5[i] = f2bf(w[((size_t)o * C_IN + c) * KS + k]);
        return;
    }
    __shared__ float red[256];
    int o = bid - W5_BLKS;
    float sum = 0.f;
    for (int i = t; i < KTOT; i += 256) {
        int k = i % KS;                    // offset layout [c][k]
        float tk = k * 0.01f;              // DT
        float off = vel[i] * tk + 0.5f * acc_in[i] * tk * tk;
        sum += off * w[(size_t)o * KTOT + i];
    }
    red[t] = sum;
    __syncthreads();
    for (int h = 128; h > 0; h >>= 1) {
        if (t < h) red[t] += red[t + h];
        __syncthreads();
    }
    if (t == 0) ebias[o] = bias[o] + red[0];

    if (o == 0) {                          // phys
        __syncthreads();
        float pv = 0.f;
        for (int i = t; i < KTOT; i += 256) {
            float v = vel[i], a = acc_in[i];
            pv += v * v + a * a;
        }
        red[t] = pv;
        __syncthreads();
        for (int h = 128; h > 0; h >>= 1) {
            if (t < h) red[t] += red[t + h];
            __syncthreads();
        }
        if (t == 0) *phys_out = 0.01f * (red[0] / (float)KTOT);
    }
}

// ---------------------------------------------------------------------------
// Main (FINAL — session best, 52us total, verified twice):
// fat-wave barrier-free K-loop + fused x-transpose.
//  - Wave tile 128o x 128l (acc[4][4] f32x16 = 256 AGPR, VGPR 208 ->
//    1 wave/SIMD). Block = 2 waves = 256o x 128l; grid 512 = 2 blocks/CU.
//  - Fused transpose+cast+swizzle builds the B tile in-prologue straight
//    from x (saves the 35MB xt round-trip; runs at the HBM floor).
//  - A: global->reg from L2-resident w5 (4 contiguous 1KB frags/step,
//    wm-disjoint), register dbuf distance 1; B: swizzled conflict-free
//    ds_read dbuf distance 1; no mid-loop barriers (compiler emits counted
//    vmcnt/lgkmcnt before first use).
// Session evidence: 17 structural variants (LDS-A staging, counted-vmcnt
// rings, phase-barriers, 2 waves/SIMD, NT stores, store-streaming x3) all
// land at conv 41.5-50us ~ 930TF = the m97-class structural ceiling, or
// spill (VGPR 256 + scratch). This configuration is the measured optimum.
// ---------------------------------------------------------------------------
__global__ __launch_bounds__(128, 1) void conv_main(const float* __restrict__ x,
                                                    const u16* __restrict__ w5,
                                                    const float* __restrict__ ebias,
                                                    float* __restrict__ out) {
    __shared__ u16 ldsx[17408];            // B tile: 136 rows x 256B = 34816 B

    int b     = blockIdx.y;
    int lbase = blockIdx.x * 128;
    int t     = threadIdx.x;               // 0..127
    int lane  = t & 63;
    int wm    = t >> 6;                    // wave = o-half (128 o each)
    int l31   = lane & 31;
    int hi    = lane >> 5;

    // A source: wave wm's 4 o-groups (g = wm*4+mi) -> contiguous 4KB/step
    const u16* alane = w5 + ((size_t)(wm * 4) * 64 + lane) * 8;

    #define LOAD_A(S, AF)                                                        \
        {                                                                        \
            const u16* p_ = alane + (size_t)(S) * 4096;                          \
            _Pragma("unroll")                                                    \
            for (int mi = 0; mi < 4; ++mi)                                       \
                AF[mi] = *reinterpret_cast<const bf16x8*>(p_ + mi * 512);        \
        }
    #define LOAD_B(S, BF)                                                        \
        {                                                                        \
            int k_ = (S) >> 3;                                                   \
            int sl_ = ((S) & 7) * 2 + hi;                                        \
            _Pragma("unroll")                                                    \
            for (int nj = 0; nj < 4; ++nj) {                                     \
                int row_  = nj * 32 + l31 + k_;                                  \
                int addr_ = row_ * 256 + ((sl_ ^ (row_ & 15)) << 4);             \
                BF[nj] = *reinterpret_cast<const bf16x8*>(ldsbase + addr_);      \
            }                                                                    \
        }
    #define MFMA16(AF, BF)                                                       \
        {                                                                        \
            _Pragma("unroll")                                                    \
            for (int mi = 0; mi < 4; ++mi)                                       \
                _Pragma("unroll")                                                \
                for (int nj = 0; nj < 4; ++nj)                                   \
                    acc[mi][nj] = __builtin_amdgcn_mfma_f32_32x32x16_bf16(       \
                        AF[mi], BF[nj], acc[mi][nj], 0, 0, 0);                   \
        }

    bf16x8 aA[4], aB[4], bA[4], bB[4];
    LOAD_A(0, aA);                         // issue A(0) first (L2 latency hidden
                                           // under the transpose below)

    // ---- fused B-tile transpose+cast+swizzle ----
    const float* xb = x + (size_t)b * C_IN * LEN;
    {
        // phase 1: rows 0..127, one row per thread; lanes = consecutive l
        int r = t;
        int l = lbase + r - PAD;
        l = l < 0 ? 0 : (l > LEN - 1 ? LEN - 1 : l);
        int key = r & 15;
        float v[16][8];
        #pragma unroll
        for (int cb = 0; cb < 16; ++cb)
            #pragma unroll
            for (int e = 0; e < 8; ++e)
                v[cb][e] = xb[(size_t)(cb * 8 + e) * LEN + l];   // coalesced
        #pragma unroll
        for (int cb = 0; cb < 16; ++cb) {
            ushort8 u;
            #pragma unroll
            for (int e = 0; e < 8; ++e) u[e] = f2bf(v[cb][e]);
            *reinterpret_cast<ushort8*>(ldsx + r * 128 + ((cb ^ key) * 8)) = u;
        }
    }
    {
        // phase 2: halo rows 128..135, (row, cblk) unit per thread
        int r  = 128 + (t & 7);
        int cb = t >> 3;                   // 0..15
        int l = lbase + r - PAD;
        l = l < 0 ? 0 : (l > LEN - 1 ? LEN - 1 : l);
        ushort8 u;
        #pragma unroll
        for (int e = 0; e < 8; ++e)
            u[e] = f2bf(xb[(size_t)(cb * 8 + e) * LEN + l]);
        *reinterpret_cast<ushort8*>(ldsx + r * 128 + ((cb ^ (r & 15)) * 8)) = u;
    }
    __syncthreads();                       // B-tile ready; the only barrier

    f32x16 acc[4][4] = {};
    const char* ldsbase = reinterpret_cast<const char*>(ldsx);
    LOAD_B(0, bA);

    #pragma unroll
    for (int s = 0; s < NSTEP; s += 2) {
        LOAD_A(s + 1, aB);
        LOAD_B(s + 1, bB);
        MFMA16(aA, bA);
        if (s + 2 < NSTEP) { LOAD_A(s + 2, aA); LOAD_B(s + 2, bA); }
        MFMA16(aB, bB);
    }

    // ---- epilogue: 32x32 D layout col = lane&31 (l), row = (reg&3)+8*(reg>>2)+4*hi
    #pragma unroll
    for (int mi = 0; mi < 4; ++mi) {
        int o0 = wm * 128 + mi * 32 + hi * 4;
        #pragma unroll
        for (int nj = 0; nj < 4; ++nj) {
            int l = lbase + nj * 32 + l31;
            #pragma unroll
            for (int q = 0; q < 4; ++q) {
                f32x4 eb = *reinterpret_cast<const f32x4*>(ebias + o0 + q * 8);
                float* op = out + (size_t)(b * C_OUT + o0 + q * 8) * LEN + l;
                #pragma unroll
                for (int p = 0; p < 4; ++p)
                    op[(size_t)p * LEN] = acc[mi][nj][q * 4 + p] + eb[p];
            }
        }
    }
    #undef LOAD_A
    #undef LOAD_B
    #undef MFMA16
}

extern "C" void kernel_launch(void* const* d_in, const int* in_sizes, int n_in,
                              void* d_out, int out_size, void* d_ws, size_t ws_size,
                              hipStream_t stream) {
    const float* x      = (const float*)d_in[0];
    const float* weight = (const float*)d_in[1];
    const float* bias   = (const float*)d_in[2];
    const float* vel    = (const float*)d_in[3];
    const float* acc    = (const float*)d_in[4];
    float* out = (float*)d_out;

    char* ws = (char*)d_ws;
    u16*  w5    = (u16*)ws;                                   // 589,824 B
    float* ebias = (float*)(ws + (size_t)C_OUT * KTOT * 2);

    hipLaunchKernelGGL(prep_all, dim3(W5_BLKS + EB_BLKS), dim3(256), 0, stream,
                       weight, bias, vel, acc, w5, ebias,
                       out + (size_t)BATCH * C_OUT * LEN);
    hipLaunchKernelGGL(conv_main, dim3(LEN / 128, BATCH), dim3(128), 0, stream,
                       x, w5, ebias, out);
}